// Round 6
// baseline (297.501 us; speedup 1.0000x reference)
//
#include <hip/hip_runtime.h>
#include <hip/hip_bf16.h>

#define BATCH 4
#define NPTS  8192
#define SPTS  2048
#define C1    128
#define C2    256
#define CIN   384   // C1+C2
#define H0    256
#define H1    128
#define NTOTF 32768.0f  // BATCH*NPTS

typedef __attribute__((ext_vector_type(8))) short bf16x8;
typedef __attribute__((ext_vector_type(4))) float f32x4;

__device__ __forceinline__ unsigned short f2bf(float x) {
  union { float f; unsigned u; } v; v.f = x;
  unsigned r = v.u + 0x7fff + ((v.u >> 16) & 1);   // RNE
  return (unsigned short)(r >> 16);
}
__device__ __forceinline__ float bf2f(unsigned short u) {
  union { unsigned u; float f; } v; v.u = ((unsigned)u) << 16; return v.f;
}
__device__ __forceinline__ float bflo(unsigned u) {
  union { unsigned x; float f; } v; v.x = u << 16; return v.f;
}
__device__ __forceinline__ float bfhi(unsigned u) {
  union { unsigned x; float f; } v; v.x = u & 0xffff0000u; return v.f;
}
__device__ __forceinline__ unsigned pack2(float lo, float hi) {
  return ((unsigned)f2bf(hi) << 16) | (unsigned)f2bf(lo);
}

// ---------------- fused prep ----------------
// [0,512):    transpose points2 (B,C2,S) fp32 -> p2tb (B,S,C2) bf16
// [512,1024): pack points1 (B,C1,N) fp32 -> Xp (B,N,C1) bf16
// [1024,1056): prepack xyz2 -> float4 (x,y,z,|c|^2)
// [1056,1184): weights fp32 -> bf16
// [1184]:     zero BN-stat accumulators (768 floats)
__global__ __launch_bounds__(256) void prep_kernel(
    const float* __restrict__ p2, unsigned short* __restrict__ p2tb,
    const float* __restrict__ xyz2, float4* __restrict__ xp,
    const float* __restrict__ w0, const float* __restrict__ w1,
    unsigned short* __restrict__ Wp,
    const float* __restrict__ p1, unsigned short* __restrict__ Xp,
    float* __restrict__ gstats) {
  __shared__ unsigned short shmem[64 * 136];
  int bid = blockIdx.x;
  int t = threadIdx.x;

  if (bid < 512) {  // ---- transpose p2 -> bf16 ----
    int b = bid >> 7, rem = bid & 127;
    int s0 = (rem >> 2) * 64, c0 = (rem & 3) * 64;
    const float* src = p2 + (size_t)b * C2 * SPTS;
    int ss = t & 63, cseg = t >> 6;
#pragma unroll
    for (int i = 0; i < 16; i++) {
      int cc = cseg + i * 4;
      shmem[ss * 72 + cc] = f2bf(src[(size_t)(c0 + cc) * SPTS + s0 + ss]);
    }
    __syncthreads();
    int s = t >> 2, chunk = t & 3;
    uint4 v0 = *(const uint4*)&shmem[s * 72 + chunk * 16];
    uint4 v1 = *(const uint4*)&shmem[s * 72 + chunk * 16 + 8];
    unsigned short* dst = p2tb + (size_t)b * SPTS * C2 + (size_t)(s0 + s) * C2 + c0 + chunk * 16;
    *(uint4*)dst = v0;
    *(uint4*)(dst + 8) = v1;
  } else if (bid < 1024) {  // ---- pack p1 -> (B,N,C1) ----
    int b2 = bid - 512;
    int b = b2 >> 7, n0 = (b2 & 127) * 64;
    int nn = t & 63, c4 = t >> 6;
#pragma unroll
    for (int i = 0; i < 32; i++) {
      int c = i * 4 + c4;
      shmem[nn * 136 + c] = f2bf(p1[((size_t)b * C1 + c) * NPTS + n0 + nn]);
    }
    __syncthreads();
    int n = t >> 2;
#pragma unroll
    for (int j = 0; j < 4; j++) {
      int ch = (t & 3) + j * 4;
      uint4 v = *(const uint4*)&shmem[n * 136 + ch * 8];
      *(uint4*)&Xp[((size_t)b * NPTS + n0 + n) * C1 + ch * 8] = v;
    }
  } else if (bid < 1056) {  // ---- prepack xyz2 ----
    int idx = (bid - 1024) * 256 + t;
    int b = idx >> 11, s = idx & (SPTS - 1);
    const float* x2 = xyz2 + (size_t)b * 3 * SPTS;
    float x = x2[s], y = x2[SPTS + s], z = x2[2 * SPTS + s];
    xp[idx] = make_float4(x, y, z, x * x + y * y + z * z);
  } else if (bid < 1184) {  // ---- pack weights ----
    int idx = ((bid - 1056) * 256 + t) * 4;
    const float* src = (idx < H0 * CIN) ? (w0 + idx) : (w1 + (idx - H0 * CIN));
    float4 v = *(const float4*)src;
    ushort4 o;
    o.x = f2bf(v.x); o.y = f2bf(v.y); o.z = f2bf(v.z); o.w = f2bf(v.w);
    *(ushort4*)(Wp + idx) = o;
  } else {  // ---- zero BN stat accumulators ----
#pragma unroll
    for (int j = 0; j < 3; j++) gstats[t + 256 * j] = 0.f;
  }
}

#define INS3(d, s, e0, e1, e2, j0, j1, j2)                        \
  {                                                               \
    bool lt0 = (d) < (e0), lt1 = (d) < (e1), lt2 = (d) < (e2);    \
    j2 = lt1 ? (j1) : (lt2 ? (s) : (j2));                         \
    j1 = lt0 ? (j0) : (lt1 ? (s) : (j1));                         \
    j0 = lt0 ? (s) : (j0);                                        \
    e2 = __builtin_amdgcn_fmed3f((d), (e1), (e2));                \
    e1 = __builtin_amdgcn_fmed3f((d), (e0), (e1));                \
    e0 = fminf((d), (e0));                                        \
  }

// ---------------- 3-NN search (R5 version) ----------------
__global__ __launch_bounds__(1024) void knn_kernel(
    const float* __restrict__ xyz1, const float4* __restrict__ xp,
    int* __restrict__ nidx, float* __restrict__ nw) {
  int b = blockIdx.y;
  int t = threadIdx.x;
  int lane = t & 63;
  int w = __builtin_amdgcn_readfirstlane(t >> 6);
  int n = blockIdx.x * 64 + lane;
  const float* x1 = xyz1 + (size_t)b * 3 * NPTS;
  float px = x1[n], py = x1[NPTS + n], pz = x1[2 * NPTS + n];

  const int CHUNK = SPTS / 16;
  int sbase = w * CHUNK;
  const float4* cp = xp + (size_t)b * SPTS + sbase;

  float d0 = 3e38f, d1 = 3e38f, d2 = 3e38f;
  int i0 = 0, i1 = 0, i2 = 0;
#pragma unroll 8
  for (int j = 0; j < CHUNK; j++) {
    float4 c = cp[j];
    float qc = fmaf(py, c.y, px * c.x);
    qc = fmaf(pz, c.z, qc);
    float d = fmaf(-2.f, qc, c.w);
    int s = sbase + j;
    INS3(d, s, d0, d1, d2, i0, i1, i2);
  }

  __shared__ float dsh[16][64][3];
  __shared__ int   ish[16][64][3];
  dsh[w][lane][0] = d0; dsh[w][lane][1] = d1; dsh[w][lane][2] = d2;
  ish[w][lane][0] = i0; ish[w][lane][1] = i1; ish[w][lane][2] = i2;
  __syncthreads();

  if (t < 256) {
    int g = t >> 6, q = t & 63;
    float e0 = 3e38f, e1 = 3e38f, e2 = 3e38f;
    int j0 = 0, j1 = 0, j2 = 0;
#pragma unroll
    for (int c = 0; c < 4; c++) {
#pragma unroll
      for (int k = 0; k < 3; k++) {
        float d = dsh[4 * g + c][q][k];
        int s = ish[4 * g + c][q][k];
        INS3(d, s, e0, e1, e2, j0, j1, j2);
      }
    }
    dsh[4 * g][q][0] = e0; dsh[4 * g][q][1] = e1; dsh[4 * g][q][2] = e2;
    ish[4 * g][q][0] = j0; ish[4 * g][q][1] = j1; ish[4 * g][q][2] = j2;
  }
  __syncthreads();

  if (t < 64) {
    float e0 = 3e38f, e1 = 3e38f, e2 = 3e38f;
    int j0 = 0, j1 = 0, j2 = 0;
#pragma unroll
    for (int c = 0; c < 4; c++) {
#pragma unroll
      for (int k = 0; k < 3; k++) {
        float d = dsh[4 * c][t][k];
        int s = ish[4 * c][t][k];
        INS3(d, s, e0, e1, e2, j0, j1, j2);
      }
    }
    float qq = px * px + py * py + pz * pz;
    float r0 = 1.f / (e0 + qq + 1e-8f);
    float r1 = 1.f / (e1 + qq + 1e-8f);
    float r2 = 1.f / (e2 + qq + 1e-8f);
    float rs = 1.f / (r0 + r1 + r2);
    int base = (b * NPTS + n) * 3;
    nidx[base + 0] = j0; nidx[base + 1] = j1; nidx[base + 2] = j2;
    nw[base + 0] = r0 * rs; nw[base + 1] = r1 * rs; nw[base + 2] = r2 * rs;
  }
}

// ---------------- GEMM1 fused: interp gather in B-staging + BN0 stats in epilogue ----------------
// Y0[b,m,n] = sum_k W0[m,k]*X[b,n,k] + b0[m];  X = [Xp1 | gather(p2tb)]
__global__ __launch_bounds__(256) void gemm1_kernel(
    const unsigned short* __restrict__ Wp, const unsigned short* __restrict__ Xp1,
    const unsigned short* __restrict__ p2tb, const int* __restrict__ nidx,
    const float* __restrict__ nw, const float* __restrict__ bias,
    unsigned short* __restrict__ Y0, float* __restrict__ gsum, float* __restrict__ gsq) {
  __shared__ unsigned short As[128 * 32];
  __shared__ unsigned short Bs[128 * 32];
  __shared__ int   sIdx[128 * 3];
  __shared__ float sW[128 * 3];
  int b = blockIdx.z;
  int n0 = blockIdx.x * 128;
  int o0 = blockIdx.y * 128;
  int t = threadIdx.x;
  int lane = t & 63;
  int w = __builtin_amdgcn_readfirstlane(t >> 6);
  int mhalf = (w & 1) * 64, nhalf = (w >> 1) * 64;

  if (t < 128) {
    int ib = (b * NPTS + n0 + t) * 3;
#pragma unroll
    for (int j = 0; j < 3; j++) { sIdx[t * 3 + j] = nidx[ib + j]; sW[t * 3 + j] = nw[ib + j]; }
  }
  __syncthreads();

  const unsigned short* p2b = p2tb + (size_t)b * SPTS * C2;
  const unsigned short* Xb  = Xp1 + (size_t)b * NPTS * C1;

  f32x4 acc[4][4] = {};
  int rA = lane >> 2;
  int cofs = (lane & 3) * 8;

  for (int k0 = 0; k0 < CIN; k0 += 32) {
#pragma unroll
    for (int q = 0; q < 2; q++) {
      int r0 = w * 32 + q * 16;
      const unsigned short* ga = Wp + (size_t)(o0 + r0 + rA) * CIN + k0 + cofs;
      __builtin_amdgcn_global_load_lds(
          (const __attribute__((address_space(1))) void*)ga,
          (__attribute__((address_space(3))) void*)(As + r0 * 32), 16, 0, 0);
    }
    if (k0 < C1) {
#pragma unroll
      for (int q = 0; q < 2; q++) {
        int r0 = w * 32 + q * 16;
        const unsigned short* gb = Xb + (size_t)(n0 + r0 + rA) * C1 + k0 + cofs;
        __builtin_amdgcn_global_load_lds(
            (const __attribute__((address_space(1))) void*)gb,
            (__attribute__((address_space(3))) void*)(Bs + r0 * 32), 16, 0, 0);
      }
    } else {
      // gather-interpolate 32 channels for this wave's 32 rows (2 lanes/row)
      int r = w * 32 + (lane >> 1);
      int cb = (k0 - C1) + (lane & 1) * 16;
      int i0 = sIdx[r * 3], i1 = sIdx[r * 3 + 1], i2 = sIdx[r * 3 + 2];
      float w0v = sW[r * 3], w1v = sW[r * 3 + 1], w2v = sW[r * 3 + 2];
      const uint4* g0 = (const uint4*)(p2b + (size_t)i0 * C2 + cb);
      const uint4* g1 = (const uint4*)(p2b + (size_t)i1 * C2 + cb);
      const uint4* g2 = (const uint4*)(p2b + (size_t)i2 * C2 + cb);
      uint4 a0 = g0[0], b0 = g0[1];
      uint4 a1 = g1[0], b1 = g1[1];
      uint4 a2 = g2[0], b2 = g2[1];
#define MIX(d0, d1, d2) pack2(w0v * bflo(d0) + w1v * bflo(d1) + w2v * bflo(d2), \
                              w0v * bfhi(d0) + w1v * bfhi(d1) + w2v * bfhi(d2))
      uint4 o0v, o1v;
      o0v.x = MIX(a0.x, a1.x, a2.x); o0v.y = MIX(a0.y, a1.y, a2.y);
      o0v.z = MIX(a0.z, a1.z, a2.z); o0v.w = MIX(a0.w, a1.w, a2.w);
      o1v.x = MIX(b0.x, b1.x, b2.x); o1v.y = MIX(b0.y, b1.y, b2.y);
      o1v.z = MIX(b0.z, b1.z, b2.z); o1v.w = MIX(b0.w, b1.w, b2.w);
#undef MIX
      uint4* dst = (uint4*)&Bs[r * 32 + (lane & 1) * 16];
      dst[0] = o0v;
      dst[1] = o1v;
    }
    __syncthreads();

    bf16x8 af[4], bfr[4];
    int mi = lane & 15, kq = (lane >> 4) * 8;
#pragma unroll
    for (int i = 0; i < 4; i++) {
      af[i]  = *(const bf16x8*)(As + (mhalf + i * 16 + mi) * 32 + kq);
      bfr[i] = *(const bf16x8*)(Bs + (nhalf + i * 16 + mi) * 32 + kq);
    }
#pragma unroll
    for (int mt = 0; mt < 4; mt++)
#pragma unroll
      for (int nt = 0; nt < 4; nt++)
        acc[mt][nt] = __builtin_amdgcn_mfma_f32_16x16x32_bf16(
            af[mt], bfr[nt], acc[mt][nt], 0, 0, 0);
    __syncthreads();
  }

  // epilogue: write Y0 bf16 + per-channel sum/sumsq atomics
  int mi = lane & 15;
  int rq = (lane >> 4) * 4;
  unsigned short* Yb = Y0 + (size_t)b * H0 * NPTS;
#pragma unroll
  for (int mt = 0; mt < 4; mt++) {
#pragma unroll
    for (int r = 0; r < 4; r++) {
      int m = o0 + mhalf + mt * 16 + rq + r;
      float bv = bias[m];
      float sv = 0.f, sq = 0.f;
#pragma unroll
      for (int nt = 0; nt < 4; nt++) {
        int n = n0 + nhalf + nt * 16 + mi;
        float v = acc[mt][nt][r] + bv;
        Yb[(size_t)m * NPTS + n] = f2bf(v);
        sv += v; sq += v * v;
      }
#pragma unroll
      for (int msk = 1; msk < 16; msk <<= 1) {
        sv += __shfl_xor(sv, msk);
        sq += __shfl_xor(sq, msk);
      }
      if (mi == 0) { atomicAdd(&gsum[m], sv); atomicAdd(&gsq[m], sq); }
    }
  }
}

// ---------------- BN0 apply + ReLU + transpose (inline stats finalize) ----------------
__global__ __launch_bounds__(256) void bn0_apply_kernel(
    const unsigned short* __restrict__ Y0, const float* __restrict__ gsum,
    const float* __restrict__ gsq, const float* __restrict__ gamma,
    const float* __restrict__ beta, unsigned short* __restrict__ X1) {
  __shared__ unsigned short tile[64][80];
  int b = blockIdx.z, o0 = blockIdx.y * 64, n0 = blockIdx.x * 64;
  int t = threadIdx.x;
  int nn = t & 63, o4 = t >> 6;
  const float inv = 1.f / NTOTF;
#pragma unroll
  for (int i = 0; i < 16; i++) {
    int o = i * 4 + o4;
    int oc = o0 + o;
    float mean = gsum[oc] * inv;
    float var = gsq[oc] * inv - mean * mean;
    float ia = gamma[oc] * rsqrtf(var + 1e-5f);
    float sh = beta[oc] - mean * ia;
    float v = bf2f(Y0[((size_t)b * H0 + oc) * NPTS + n0 + nn]);
    v = fmaxf(v * ia + sh, 0.f);
    tile[nn][o] = f2bf(v);
  }
  __syncthreads();
  int n = t >> 2;
#pragma unroll
  for (int j = 0; j < 2; j++) {
    int ch = (t & 3) + j * 4;
    uint4 v = *(const uint4*)&tile[n][ch * 8];
    *(uint4*)&X1[((size_t)b * NPTS + n0 + n) * H0 + o0 + ch * 8] = v;
  }
}

// ---------------- GEMM2: fp32 out + BN1 stats in epilogue ----------------
__global__ __launch_bounds__(256) void gemm2_kernel(
    const unsigned short* __restrict__ A, const unsigned short* __restrict__ X,
    const float* __restrict__ bias, float* __restrict__ Y,
    float* __restrict__ gsum, float* __restrict__ gsq) {
  __shared__ unsigned short As[128 * 32];
  __shared__ unsigned short Bs[128 * 32];
  int b = blockIdx.z;
  int n0 = blockIdx.x * 128;
  int t = threadIdx.x;
  int lane = t & 63;
  int w = __builtin_amdgcn_readfirstlane(t >> 6);
  int mhalf = (w & 1) * 64, nhalf = (w >> 1) * 64;
  const unsigned short* Xb = X + (size_t)b * NPTS * H0;

  f32x4 acc[4][4] = {};
  int rA = lane >> 2;
  int cofs = (lane & 3) * 8;

  for (int k0 = 0; k0 < H0; k0 += 32) {
#pragma unroll
    for (int q = 0; q < 2; q++) {
      int r0 = w * 32 + q * 16;
      const unsigned short* ga = A + (size_t)(r0 + rA) * H0 + k0 + cofs;
      __builtin_amdgcn_global_load_lds(
          (const __attribute__((address_space(1))) void*)ga,
          (__attribute__((address_space(3))) void*)(As + r0 * 32), 16, 0, 0);
      const unsigned short* gb = Xb + (size_t)(n0 + r0 + rA) * H0 + k0 + cofs;
      __builtin_amdgcn_global_load_lds(
          (const __attribute__((address_space(1))) void*)gb,
          (__attribute__((address_space(3))) void*)(Bs + r0 * 32), 16, 0, 0);
    }
    __syncthreads();

    bf16x8 af[4], bfr[4];
    int mi = lane & 15, kq = (lane >> 4) * 8;
#pragma unroll
    for (int i = 0; i < 4; i++) {
      af[i]  = *(const bf16x8*)(As + (mhalf + i * 16 + mi) * 32 + kq);
      bfr[i] = *(const bf16x8*)(Bs + (nhalf + i * 16 + mi) * 32 + kq);
    }
#pragma unroll
    for (int mt = 0; mt < 4; mt++)
#pragma unroll
      for (int nt = 0; nt < 4; nt++)
        acc[mt][nt] = __builtin_amdgcn_mfma_f32_16x16x32_bf16(
            af[mt], bfr[nt], acc[mt][nt], 0, 0, 0);
    __syncthreads();
  }

  int mi = lane & 15;
  int rq = (lane >> 4) * 4;
  float* Yb = Y + (size_t)b * H1 * NPTS;
#pragma unroll
  for (int mt = 0; mt < 4; mt++) {
#pragma unroll
    for (int r = 0; r < 4; r++) {
      int m = mhalf + mt * 16 + rq + r;
      float bv = bias[m];
      float sv = 0.f, sq = 0.f;
#pragma unroll
      for (int nt = 0; nt < 4; nt++) {
        int n = n0 + nhalf + nt * 16 + mi;
        float v = acc[mt][nt][r] + bv;
        Yb[(size_t)m * NPTS + n] = v;
        sv += v; sq += v * v;
      }
#pragma unroll
      for (int msk = 1; msk < 16; msk <<= 1) {
        sv += __shfl_xor(sv, msk);
        sq += __shfl_xor(sq, msk);
      }
      if (mi == 0) { atomicAdd(&gsum[m], sv); atomicAdd(&gsq[m], sq); }
    }
  }
}

// ---------------- final BN+ReLU in-place on d_out (inline stats finalize) ----------------
__global__ __launch_bounds__(256) void bn_apply_kernel(
    float* __restrict__ Y, const float* __restrict__ gsum, const float* __restrict__ gsq,
    const float* __restrict__ gamma, const float* __restrict__ beta) {
  int idx = blockIdx.x * 256 + threadIdx.x;
  int i = idx * 4;
  int c = (i >> 13) & (H1 - 1);
  const float inv = 1.f / NTOTF;
  float mean = gsum[c] * inv;
  float var = gsq[c] * inv - mean * mean;
  float ia = gamma[c] * rsqrtf(var + 1e-5f);
  float sh = beta[c] - mean * ia;
  float4 v = *(float4*)(Y + i);
  v.x = fmaxf(v.x * ia + sh, 0.f);
  v.y = fmaxf(v.y * ia + sh, 0.f);
  v.z = fmaxf(v.z * ia + sh, 0.f);
  v.w = fmaxf(v.w * ia + sh, 0.f);
  *(float4*)(Y + i) = v;
}

extern "C" void kernel_launch(void* const* d_in, const int* in_sizes, int n_in,
                              void* d_out, int out_size, void* d_ws, size_t ws_size,
                              hipStream_t stream) {
  const float* xyz1    = (const float*)d_in[0];
  const float* xyz2    = (const float*)d_in[1];
  const float* points1 = (const float*)d_in[2];
  const float* points2 = (const float*)d_in[3];
  const float* w0      = (const float*)d_in[4];
  const float* b0      = (const float*)d_in[5];
  const float* gamma0  = (const float*)d_in[6];
  const float* beta0   = (const float*)d_in[7];
  const float* w1      = (const float*)d_in[8];
  const float* b1      = (const float*)d_in[9];
  const float* gamma1  = (const float*)d_in[10];
  const float* beta1   = (const float*)d_in[11];
  float* out = (float*)d_out;

  char* ws = (char*)d_ws;
  unsigned short* p2tb = (unsigned short*)ws;  ws += (size_t)BATCH * SPTS * C2 * 2;   // 4.2 MB
  unsigned short* Xp = (unsigned short*)ws;    ws += (size_t)BATCH * NPTS * C1 * 2;   // 8.4 MB
  unsigned short* Y0 = (unsigned short*)ws;    ws += (size_t)BATCH * H0 * NPTS * 2;   // 16.8 MB
  unsigned short* X1 = (unsigned short*)ws;    ws += (size_t)BATCH * NPTS * H0 * 2;   // 16.8 MB
  unsigned short* Wp = (unsigned short*)ws;    ws += (size_t)(H0 * CIN + H1 * H0) * 2;
  int* nidx = (int*)ws;                        ws += (size_t)BATCH * NPTS * 3 * 4;
  float* nw = (float*)ws;                      ws += (size_t)BATCH * NPTS * 3 * 4;
  float4* xyz2p = (float4*)(((uintptr_t)ws + 15) & ~(uintptr_t)15);
  ws = (char*)xyz2p + (size_t)BATCH * SPTS * 16;
  float* gstats = (float*)ws;                  ws += 768 * 4;
  float* gsum0 = gstats;        // 256
  float* gsq0  = gstats + 256;  // 256
  float* gsum1 = gstats + 512;  // 128
  float* gsq1  = gstats + 640;  // 128
  (void)ws_size; (void)in_sizes; (void)n_in; (void)out_size;

  prep_kernel<<<dim3(1185), 256, 0, stream>>>(points2, p2tb, xyz2, xyz2p,
                                              w0, w1, Wp, points1, Xp, gstats);
  knn_kernel<<<dim3(NPTS / 64, BATCH), 1024, 0, stream>>>(xyz1, xyz2p, nidx, nw);
  gemm1_kernel<<<dim3(NPTS / 128, H0 / 128, BATCH), 256, 0, stream>>>(
      Wp, Xp, p2tb, nidx, nw, b0, Y0, gsum0, gsq0);
  bn0_apply_kernel<<<dim3(NPTS / 64, H0 / 64, BATCH), 256, 0, stream>>>(
      Y0, gsum0, gsq0, gamma0, beta0, X1);
  gemm2_kernel<<<dim3(NPTS / 128, 1, BATCH), 256, 0, stream>>>(
      Wp + H0 * CIN, X1, b1, out, gsum1, gsq1);
  bn_apply_kernel<<<dim3(BATCH * H1 * NPTS / 1024), 256, 0, stream>>>(
      out, gsum1, gsq1, gamma1, beta1);
}